// Round 5
// baseline (104.564 us; speedup 1.0000x reference)
//
#include <hip/hip_runtime.h>
#include <math.h>

// GAT layer. B=16, N=1024, IN=128, H=2, D=64.
// out = elu( softmax_m(leakyrelu(e_src[n]+e_dst[m])) @ hp + h )
//
// Two launches (split at the grid-wide hp dependency; no cooperative launch):
// gat_hp (512 blocks): per-block W bf16-pack into LDS, then hp = h @ Wcat via
//   mfma_16x16x32_bf16 -> hpB (global, k-packed bf16) + es/ed fused.
// gat_att (1024 blocks): block = (bh = blk&31, 32-row n-tile = blk>>5).
//   2 A-frag rows share every B-frag load (halves hpB L2 traffic); 4 waves
//   split m 4-way with register double-buffer; P in registers:
//   P = 2^( max(x,0.2x) - M ), closed-form row max M = L(s_n'+dmax');
//   partials combined via LDS stride-35 (conflict-free), elu epilogue.
// Note: dur_us carries ~46 us of fixed harness reset traffic (256 MiB d_ws
// re-poison fill) — kernel-side budget here is ~14 us.

#define LOG2E 1.44269504088896340736f

typedef __bf16 bf16x8 __attribute__((ext_vector_type(8)));
typedef float floatx4 __attribute__((ext_vector_type(4)));

union U16x8 { uint4 u; bf16x8 b; };

__device__ __forceinline__ unsigned short f2bf(float f) {
    union { __bf16 b; unsigned short u; } x;
    x.b = (__bf16)f;
    return x.u;
}

// ---------------------------------------------------------------------------
// Kernel 1: hp = h @ Wcat (+ es/ed). 512 blocks x 256 thr.
// wave = (16-row tile, head); W packed per block into LDS.
// ---------------------------------------------------------------------------
__global__ __launch_bounds__(256) void gat_hp(
    const float* __restrict__ hg,        // (16384,128)
    const float* __restrict__ Wg,        // (2,128,64)
    const float* __restrict__ ag,        // (2,128)
    unsigned short* __restrict__ hpB,    // (32,128,64,8) bf16 ws
    float* __restrict__ es_g,            // (32,1024) ws
    float* __restrict__ ed_g)            // (32,1024) ws
{
    __shared__ unsigned short wp[16 * 128 * 8];   // 32 KB packed W

    const int t = threadIdx.x;
    const int lane = t & 63;
    const int col = lane & 15, quad = lane >> 4;

    // W pack: wp[((k>>3)*128 + head*64 + d)*8 + (k&7)] = bf16(W[head][k][d])
#pragma unroll
    for (int i = 0; i < 16; ++i) {
        int lin = (i * 256 + t) * 4;              // float4-coalesced over 16384
        int head = lin >> 13, k = (lin >> 6) & 127, d = lin & 63;
        float4 v = *(const float4*)(Wg + lin);
        int base = ((k >> 3) * 128 + head * 64 + d) * 8 + (k & 7);
        wp[base]      = f2bf(v.x);
        wp[base + 8]  = f2bf(v.y);
        wp[base + 16] = f2bf(v.z);
        wp[base + 24] = f2bf(v.w);
    }
    __syncthreads();

    const int wv = blockIdx.x * 4 + (t >> 6);   // 0..2047
    const int rt = wv >> 1;                     // 16-row tile, 0..1023
    const int half = wv & 1;                    // head
    const int n0 = rt * 16;

    floatx4 acc[4];
#pragma unroll
    for (int ct = 0; ct < 4; ++ct) acc[ct] = (floatx4){0.f, 0.f, 0.f, 0.f};

    const float* hrow = hg + (size_t)(n0 + col) * 128;
    const uint4* wl = (const uint4*)wp;
#pragma unroll
    for (int kq = 0; kq < 4; ++kq) {
        float4 h0 = *(const float4*)(hrow + kq * 32 + quad * 8);
        float4 h1 = *(const float4*)(hrow + kq * 32 + quad * 8 + 4);
        bf16x8 af;
        af[0] = (__bf16)h0.x; af[1] = (__bf16)h0.y;
        af[2] = (__bf16)h0.z; af[3] = (__bf16)h0.w;
        af[4] = (__bf16)h1.x; af[5] = (__bf16)h1.y;
        af[6] = (__bf16)h1.z; af[7] = (__bf16)h1.w;
        const int u = (kq * 4 + quad) * 128 + half * 64;
#pragma unroll
        for (int ct = 0; ct < 4; ++ct) {
            U16x8 bu; bu.u = wl[u + ct * 16 + col];
            acc[ct] = __builtin_amdgcn_mfma_f32_16x16x32_bf16(af, bu.b, acc[ct], 0, 0, 0);
        }
    }

    const int b = n0 >> 10;
    const int nloc = n0 & 1023;
    const int bh = b * 2 + half;

    // fused e_src / e_dst from fp32 accumulators (a: tiny, L1-resident)
    float esr[4] = {0.f, 0.f, 0.f, 0.f}, edr[4] = {0.f, 0.f, 0.f, 0.f};
#pragma unroll
    for (int ct = 0; ct < 4; ++ct) {
        int d = ct * 16 + col;
        float as = ag[half * 128 + d];
        float ad = ag[half * 128 + 64 + d];
#pragma unroll
        for (int r = 0; r < 4; ++r) {
            esr[r] = fmaf(acc[ct][r], as, esr[r]);
            edr[r] = fmaf(acc[ct][r], ad, edr[r]);
        }
    }
#pragma unroll
    for (int off = 1; off <= 8; off <<= 1) {
#pragma unroll
        for (int r = 0; r < 4; ++r) {
            esr[r] += __shfl_xor(esr[r], off, 64);
            edr[r] += __shfl_xor(edr[r], off, 64);
        }
    }
    if (col == 0) {
        size_t base = (size_t)bh * 1024 + nloc + quad * 4;
#pragma unroll
        for (int r = 0; r < 4; ++r) {
            es_g[base + r] = esr[r];
            ed_g[base + r] = edr[r];
        }
    }

    // hpB store: k-packed layout [(bh*128+g)*64 + d]*8 + (m%8)
    const int gloc = (nloc >> 3) + (quad >> 1);
#pragma unroll
    for (int ct = 0; ct < 4; ++ct) {
        int d = ct * 16 + col;
        uint2 pk;
        pk.x = (unsigned)f2bf(acc[ct][0]) | ((unsigned)f2bf(acc[ct][1]) << 16);
        pk.y = (unsigned)f2bf(acc[ct][2]) | ((unsigned)f2bf(acc[ct][3]) << 16);
        size_t idx = ((size_t)(bh * 128 + gloc) * 64 + d) * 8 + (quad & 1) * 4;
        *(uint2*)(hpB + idx) = pk;
    }
}

// ---------------------------------------------------------------------------
// Kernel 2: attention. 1024 blocks x 256 thr.
// block = (bh = blk&31, nt = blk>>5 -> 32-row tile); 4 waves split m 4-way.
// ---------------------------------------------------------------------------
__global__ __launch_bounds__(256, 4) void gat_att(
    const float* __restrict__ hg,
    const unsigned short* __restrict__ hpB,
    const float* __restrict__ es_g,
    const float* __restrict__ ed_g,
    float* __restrict__ out)
{
    __shared__ float red[4 * 64 * 35];   // 35.8 KB: [wave][lane][2x16 acc + 2 lsum]

    const int t = threadIdx.x;
    const int lane = t & 63;
    const int w = t >> 6;
    const int bh = blockIdx.x & 31;      // same-bh blocks -> same XCD
    const int nt = blockIdx.x >> 5;      // 0..31
    const int b = bh >> 1, hh = bh & 1;
    const int n0 = nt * 32;
    const int col = lane & 15, quad = lane >> 4;

    const float* edrow = ed_g + (size_t)bh * 1024;

    // dmax over full row (per-wave, no barrier)
    float mx = -1e30f;
#pragma unroll
    for (int i = 0; i < 4; ++i) {
        float4 v = *(const float4*)(edrow + lane * 16 + i * 4);
        mx = fmaxf(mx, fmaxf(fmaxf(v.x, v.y), fmaxf(v.z, v.w)));
    }
#pragma unroll
    for (int off = 1; off < 64; off <<= 1) mx = fmaxf(mx, __shfl_xor(mx, off, 64));
    const float mxl = mx * LOG2E;

    // two 16-row subtiles; closed-form row max per subtile (log2 domain)
    const float s2a = es_g[(size_t)bh * 1024 + n0 + col] * LOG2E;
    const float s2b = es_g[(size_t)bh * 1024 + n0 + 16 + col] * LOG2E;
    const float x0a = s2a + mxl, x0b = s2b + mxl;
    const float Ma = fmaxf(x0a, 0.2f * x0a), Mb = fmaxf(x0b, 0.2f * x0b);
    const float s2ma = s2a - Ma, s5ma = 0.2f * s2a - Ma;
    const float s2mb = s2b - Mb, s5mb = 0.2f * s2b - Mb;
    const float K = LOG2E, K5 = 0.2f * LOG2E;

    floatx4 acc0[4], acc1[4];
#pragma unroll
    for (int ct = 0; ct < 4; ++ct) {
        acc0[ct] = (floatx4){0.f, 0.f, 0.f, 0.f};
        acc1[ct] = (floatx4){0.f, 0.f, 0.f, 0.f};
    }
    float ls0 = 0.f, ls1 = 0.f;

    const uint4* hb = (const uint4*)hpB + (size_t)bh * 8192;
    const int mbase = w * 256;            // 4-way split-m

    // register double-buffer: preload chunk 0
    float4 d0 = *(const float4*)(edrow + mbase + quad * 8);
    float4 d1 = *(const float4*)(edrow + mbase + quad * 8 + 4);
    int gm = (mbase >> 3) + quad;
    uint4 bu0 = hb[gm * 64 + col];
    uint4 bu1 = hb[gm * 64 + 16 + col];
    uint4 bu2 = hb[gm * 64 + 32 + col];
    uint4 bu3 = hb[gm * 64 + 48 + col];

#pragma unroll
    for (int i = 0; i < 8; ++i) {
        float4 c0 = d0, c1 = d1;
        uint4 cb0 = bu0, cb1 = bu1, cb2 = bu2, cb3 = bu3;
        if (i < 7) {
            int m1 = mbase + (i + 1) * 32;
            d0 = *(const float4*)(edrow + m1 + quad * 8);
            d1 = *(const float4*)(edrow + m1 + quad * 8 + 4);
            gm = (m1 >> 3) + quad;
            bu0 = hb[gm * 64 + col];
            bu1 = hb[gm * 64 + 16 + col];
            bu2 = hb[gm * 64 + 32 + col];
            bu3 = hb[gm * 64 + 48 + col];
        }
        float dv[8] = {c0.x, c0.y, c0.z, c0.w, c1.x, c1.y, c1.z, c1.w};
        bf16x8 af0, af1;
#pragma unroll
        for (int j = 0; j < 8; ++j) {
            float pa = __builtin_amdgcn_exp2f(fmaxf(fmaf(dv[j], K, s2ma), fmaf(dv[j], K5, s5ma)));
            float pb = __builtin_amdgcn_exp2f(fmaxf(fmaf(dv[j], K, s2mb), fmaf(dv[j], K5, s5mb)));
            ls0 += pa; ls1 += pb;
            af0[j] = (__bf16)pa;
            af1[j] = (__bf16)pb;
        }
        U16x8 u0; u0.u = cb0;
        U16x8 u1; u1.u = cb1;
        U16x8 u2; u2.u = cb2;
        U16x8 u3; u3.u = cb3;
        acc0[0] = __builtin_amdgcn_mfma_f32_16x16x32_bf16(af0, u0.b, acc0[0], 0, 0, 0);
        acc1[0] = __builtin_amdgcn_mfma_f32_16x16x32_bf16(af1, u0.b, acc1[0], 0, 0, 0);
        acc0[1] = __builtin_amdgcn_mfma_f32_16x16x32_bf16(af0, u1.b, acc0[1], 0, 0, 0);
        acc1[1] = __builtin_amdgcn_mfma_f32_16x16x32_bf16(af1, u1.b, acc1[1], 0, 0, 0);
        acc0[2] = __builtin_amdgcn_mfma_f32_16x16x32_bf16(af0, u2.b, acc0[2], 0, 0, 0);
        acc1[2] = __builtin_amdgcn_mfma_f32_16x16x32_bf16(af1, u2.b, acc1[2], 0, 0, 0);
        acc0[3] = __builtin_amdgcn_mfma_f32_16x16x32_bf16(af0, u3.b, acc0[3], 0, 0, 0);
        acc1[3] = __builtin_amdgcn_mfma_f32_16x16x32_bf16(af1, u3.b, acc1[3], 0, 0, 0);
    }

    // per-wave row-sums over this m-range
    ls0 += __shfl_xor(ls0, 16, 64); ls0 += __shfl_xor(ls0, 32, 64);
    ls1 += __shfl_xor(ls1, 16, 64); ls1 += __shfl_xor(ls1, 32, 64);

    // write partials (stride 35: conflict-free scalar access)
    float* myred = red + (w * 64 + lane) * 35;
#pragma unroll
    for (int ct = 0; ct < 4; ++ct)
#pragma unroll
        for (int r = 0; r < 4; ++r) {
            myred[ct * 4 + r]      = acc0[ct][r];
            myred[16 + ct * 4 + r] = acc1[ct][r];
        }
    myred[32] = ls0;
    myred[33] = ls1;
    __syncthreads();

    // combine: wave owns (subtile = w&1, ct pair = w>>1)
    const int tile = w & 1;
    const int ctp = w >> 1;
    float ltot = 0.f;
#pragma unroll
    for (int v4 = 0; v4 < 4; ++v4)
        ltot += red[(v4 * 64 + lane) * 35 + 32 + tile];
    float inv[4];
#pragma unroll
    for (int r = 0; r < 4; ++r)
        inv[r] = __builtin_amdgcn_rcpf(__shfl(ltot, quad * 4 + r, 16));

#pragma unroll
    for (int cti = 0; cti < 2; ++cti) {
        const int ct = ctp * 2 + cti;
        float facc[4] = {0.f, 0.f, 0.f, 0.f};
#pragma unroll
        for (int v4 = 0; v4 < 4; ++v4) {
            const float* rr = red + (v4 * 64 + lane) * 35 + tile * 16 + ct * 4;
#pragma unroll
            for (int r = 0; r < 4; ++r) facc[r] += rr[r];
        }
#pragma unroll
        for (int r = 0; r < 4; ++r) {
            int n = n0 + tile * 16 + quad * 4 + r;
            size_t off = (size_t)(b * 1024 + n) * 128 + hh * 64 + ct * 16 + col;
            float vv = facc[r] * inv[r] + hg[off];
            out[off] = vv > 0.f ? vv : __builtin_amdgcn_exp2f(vv * LOG2E) - 1.f;
        }
    }
}

// ---------------------------------------------------------------------------
extern "C" void kernel_launch(void* const* d_in, const int* in_sizes, int n_in,
                              void* d_out, int out_size, void* d_ws, size_t ws_size,
                              hipStream_t stream) {
    const float* h = (const float*)d_in[0];   // (16,1024,128)
    const float* W = (const float*)d_in[1];   // (2,128,64)
    const float* a = (const float*)d_in[2];   // (2,128,1)
    float* out = (float*)d_out;

    unsigned short* hpB = (unsigned short*)d_ws;                    // 4 MB
    float* es  = (float*)((char*)d_ws + (4u << 20));                // 128 KB
    float* ed  = es + 32 * 1024;                                    // 128 KB

    gat_hp<<<512, 256, 0, stream>>>(h, W, a, hpB, es, ed);
    gat_att<<<1024, 256, 0, stream>>>(h, hpB, es, ed, out);
}

// Round 6
// 82.062 us; speedup vs baseline: 1.2742x; 1.2742x over previous
//
#include <hip/hip_runtime.h>
#include <math.h>

// GAT layer. B=16, N=1024, IN=128, H=2, D=64.
// out = elu( softmax_m(leakyrelu(e_src[n]+e_dst[m])) @ hp + h )
//
// gat_prep (16 blocks): Wp[k/8][c][k%8] bf16 pack + acat  (round-3 verbatim).
// gat_hp (512 blocks): hp = h @ Wcat via mfma_16x16x32_bf16 -> hpB k-packed
//   bf16 + es/ed fused (round-3 verbatim).
// gat_att (1024 blocks): block = (bh, 32-row n-tile); 2 A-frag subtiles share
//   every B-frag load; 4 waves split m 4-way, register double-buffer;
//   P = 2^( max(x,0.2x) - M ) in registers, closed-form row max.
//   __launch_bounds__(256,2): VGPR cap 256 — round 5's (256,4) forced spills
//   (~140-170 VGPR needed vs 128 cap) and cost ~+20 us.
// dur_us carries ~46 us fixed harness reset traffic (256 MiB d_ws re-poison).

#define LOG2E 1.44269504088896340736f

typedef __bf16 bf16x8 __attribute__((ext_vector_type(8)));
typedef float floatx4 __attribute__((ext_vector_type(4)));

union U16x8 { uint4 u; bf16x8 b; };

__device__ __forceinline__ unsigned short f2bf(float f) {
    union { __bf16 b; unsigned short u; } x;
    x.b = (__bf16)f;
    return x.u;
}

// ---------------------------------------------------------------------------
// prep: pack W to bf16 k-major-8 layout; build acat. 16 blocks x 256.
// ---------------------------------------------------------------------------
__global__ __launch_bounds__(256) void gat_prep(
    const float* __restrict__ Wg,   // (2,128,64)
    const float* __restrict__ ag,   // (2,128)
    unsigned short* __restrict__ Wp,  // (16,128,8) bf16
    float* __restrict__ acat)         // (256)
{
    const int t = threadIdx.x;
    const int base = blockIdx.x * 1024;
#pragma unroll
    for (int i = 0; i < 4; ++i) {
        int idx = base + i * 256 + t;           // 16384 total
        int c = idx & 127, k = idx >> 7;
        float v = Wg[(c >> 6) * 8192 + k * 64 + (c & 63)];
        Wp[((k >> 3) * 128 + c) * 8 + (k & 7)] = f2bf(v);
    }
    if (blockIdx.x == 0 && t < 128) {
        acat[t]       = ag[(t >> 6) * 128 + (t & 63)];
        acat[128 + t] = ag[(t >> 6) * 128 + 64 + (t & 63)];
    }
}

// ---------------------------------------------------------------------------
// Kernel A: hp = h @ Wcat. 512 blocks x 256 thr; wave = (16-row tile, head).
// ---------------------------------------------------------------------------
__global__ __launch_bounds__(256) void gat_hp(
    const float* __restrict__ hg,        // (16384,128)
    const unsigned short* __restrict__ Wp,
    const float* __restrict__ acat,
    unsigned short* __restrict__ hpB,    // (32,128,64,8) bf16
    float* __restrict__ es_g,            // (32,1024)
    float* __restrict__ ed_g)            // (32,1024)
{
    const int t = threadIdx.x;
    const int lane = t & 63;
    const int wv = blockIdx.x * 4 + (t >> 6);   // 0..2047
    const int rt = wv >> 1;                     // global 16-row tile, 0..1023
    const int half = wv & 1;                    // head
    const int n0 = rt * 16;
    const int col = lane & 15, quad = lane >> 4;

    floatx4 acc[4];
#pragma unroll
    for (int ct = 0; ct < 4; ++ct) acc[ct] = (floatx4){0.f, 0.f, 0.f, 0.f};

    const float* hrow = hg + (size_t)(n0 + col) * 128;
    const uint4* wp4 = (const uint4*)Wp;
#pragma unroll
    for (int kq = 0; kq < 4; ++kq) {
        float4 h0 = *(const float4*)(hrow + kq * 32 + quad * 8);
        float4 h1 = *(const float4*)(hrow + kq * 32 + quad * 8 + 4);
        bf16x8 af;
        af[0] = (__bf16)h0.x; af[1] = (__bf16)h0.y;
        af[2] = (__bf16)h0.z; af[3] = (__bf16)h0.w;
        af[4] = (__bf16)h1.x; af[5] = (__bf16)h1.y;
        af[6] = (__bf16)h1.z; af[7] = (__bf16)h1.w;
        const uint4* wbase = wp4 + (size_t)(kq * 4 + quad) * 128 + half * 64;
#pragma unroll
        for (int ct = 0; ct < 4; ++ct) {
            U16x8 bu; bu.u = wbase[ct * 16 + col];
            acc[ct] = __builtin_amdgcn_mfma_f32_16x16x32_bf16(af, bu.b, acc[ct], 0, 0, 0);
        }
    }

    const int b = n0 >> 10;
    const int nloc = n0 & 1023;
    const int bh = b * 2 + half;

    // fused e_src / e_dst from fp32 accumulators
    float esr[4] = {0.f, 0.f, 0.f, 0.f}, edr[4] = {0.f, 0.f, 0.f, 0.f};
#pragma unroll
    for (int ct = 0; ct < 4; ++ct) {
        int c = half * 64 + ct * 16 + col;
        float as = acat[c], ad = acat[128 + c];
#pragma unroll
        for (int r = 0; r < 4; ++r) {
            esr[r] = fmaf(acc[ct][r], as, esr[r]);
            edr[r] = fmaf(acc[ct][r], ad, edr[r]);
        }
    }
#pragma unroll
    for (int off = 1; off <= 8; off <<= 1) {
#pragma unroll
        for (int r = 0; r < 4; ++r) {
            esr[r] += __shfl_xor(esr[r], off, 64);
            edr[r] += __shfl_xor(edr[r], off, 64);
        }
    }
    if (col == 0) {
        size_t base = (size_t)bh * 1024 + nloc + quad * 4;
#pragma unroll
        for (int r = 0; r < 4; ++r) {
            es_g[base + r] = esr[r];
            ed_g[base + r] = edr[r];
        }
    }

    // hpB stores: rows n = n0 + quad*4 + r; n%8 = (quad&1)*4 + r
    const int gloc = (nloc >> 3) + (quad >> 1);
#pragma unroll
    for (int ct = 0; ct < 4; ++ct) {
        int d = ct * 16 + col;
        uint2 pk;
        pk.x = (unsigned)f2bf(acc[ct][0]) | ((unsigned)f2bf(acc[ct][1]) << 16);
        pk.y = (unsigned)f2bf(acc[ct][2]) | ((unsigned)f2bf(acc[ct][3]) << 16);
        size_t idx = ((size_t)(bh * 128 + gloc) * 64 + d) * 8 + (quad & 1) * 4;
        *(uint2*)(hpB + idx) = pk;
    }
}

// ---------------------------------------------------------------------------
// Kernel 2: attention. 1024 blocks x 256 thr.
// block = (bh = blk&31, nt = blk>>5 -> 32-row tile); 4 waves split m 4-way.
// ---------------------------------------------------------------------------
__global__ __launch_bounds__(256, 2) void gat_att(
    const float* __restrict__ hg,
    const unsigned short* __restrict__ hpB,
    const float* __restrict__ es_g,
    const float* __restrict__ ed_g,
    float* __restrict__ out)
{
    __shared__ float red[4 * 64 * 35];   // 35.8 KB: [wave][lane][2x16 acc + 2 lsum]

    const int t = threadIdx.x;
    const int lane = t & 63;
    const int w = t >> 6;
    const int bh = blockIdx.x & 31;      // same-bh blocks -> same XCD
    const int nt = blockIdx.x >> 5;      // 0..31
    const int b = bh >> 1, hh = bh & 1;
    const int n0 = nt * 32;
    const int col = lane & 15, quad = lane >> 4;

    const float* edrow = ed_g + (size_t)bh * 1024;

    // dmax over full row (per-wave, no barrier)
    float mx = -1e30f;
#pragma unroll
    for (int i = 0; i < 4; ++i) {
        float4 v = *(const float4*)(edrow + lane * 16 + i * 4);
        mx = fmaxf(mx, fmaxf(fmaxf(v.x, v.y), fmaxf(v.z, v.w)));
    }
#pragma unroll
    for (int off = 1; off < 64; off <<= 1) mx = fmaxf(mx, __shfl_xor(mx, off, 64));
    const float mxl = mx * LOG2E;

    // two 16-row subtiles; closed-form row max per subtile (log2 domain)
    const float s2a = es_g[(size_t)bh * 1024 + n0 + col] * LOG2E;
    const float s2b = es_g[(size_t)bh * 1024 + n0 + 16 + col] * LOG2E;
    const float x0a = s2a + mxl, x0b = s2b + mxl;
    const float Ma = fmaxf(x0a, 0.2f * x0a), Mb = fmaxf(x0b, 0.2f * x0b);
    const float s2ma = s2a - Ma, s5ma = 0.2f * s2a - Ma;
    const float s2mb = s2b - Mb, s5mb = 0.2f * s2b - Mb;
    const float K = LOG2E, K5 = 0.2f * LOG2E;

    floatx4 acc0[4], acc1[4];
#pragma unroll
    for (int ct = 0; ct < 4; ++ct) {
        acc0[ct] = (floatx4){0.f, 0.f, 0.f, 0.f};
        acc1[ct] = (floatx4){0.f, 0.f, 0.f, 0.f};
    }
    float ls0 = 0.f, ls1 = 0.f;

    const uint4* hb = (const uint4*)hpB + (size_t)bh * 8192;
    const int mbase = w * 256;            // 4-way split-m

    // register double-buffer: preload chunk 0
    float4 d0 = *(const float4*)(edrow + mbase + quad * 8);
    float4 d1 = *(const float4*)(edrow + mbase + quad * 8 + 4);
    int gm = (mbase >> 3) + quad;
    uint4 bu0 = hb[gm * 64 + col];
    uint4 bu1 = hb[gm * 64 + 16 + col];
    uint4 bu2 = hb[gm * 64 + 32 + col];
    uint4 bu3 = hb[gm * 64 + 48 + col];

#pragma unroll
    for (int i = 0; i < 8; ++i) {
        float4 c0 = d0, c1 = d1;
        uint4 cb0 = bu0, cb1 = bu1, cb2 = bu2, cb3 = bu3;
        if (i < 7) {
            int m1 = mbase + (i + 1) * 32;
            d0 = *(const float4*)(edrow + m1 + quad * 8);
            d1 = *(const float4*)(edrow + m1 + quad * 8 + 4);
            gm = (m1 >> 3) + quad;
            bu0 = hb[gm * 64 + col];
            bu1 = hb[gm * 64 + 16 + col];
            bu2 = hb[gm * 64 + 32 + col];
            bu3 = hb[gm * 64 + 48 + col];
        }
        float dv[8] = {c0.x, c0.y, c0.z, c0.w, c1.x, c1.y, c1.z, c1.w};
        bf16x8 af0, af1;
#pragma unroll
        for (int j = 0; j < 8; ++j) {
            float pa = __builtin_amdgcn_exp2f(fmaxf(fmaf(dv[j], K, s2ma), fmaf(dv[j], K5, s5ma)));
            float pb = __builtin_amdgcn_exp2f(fmaxf(fmaf(dv[j], K, s2mb), fmaf(dv[j], K5, s5mb)));
            ls0 += pa; ls1 += pb;
            af0[j] = (__bf16)pa;
            af1[j] = (__bf16)pb;
        }
        U16x8 u0; u0.u = cb0;
        U16x8 u1; u1.u = cb1;
        U16x8 u2; u2.u = cb2;
        U16x8 u3; u3.u = cb3;
        acc0[0] = __builtin_amdgcn_mfma_f32_16x16x32_bf16(af0, u0.b, acc0[0], 0, 0, 0);
        acc1[0] = __builtin_amdgcn_mfma_f32_16x16x32_bf16(af1, u0.b, acc1[0], 0, 0, 0);
        acc0[1] = __builtin_amdgcn_mfma_f32_16x16x32_bf16(af0, u1.b, acc0[1], 0, 0, 0);
        acc1[1] = __builtin_amdgcn_mfma_f32_16x16x32_bf16(af1, u1.b, acc1[1], 0, 0, 0);
        acc0[2] = __builtin_amdgcn_mfma_f32_16x16x32_bf16(af0, u2.b, acc0[2], 0, 0, 0);
        acc1[2] = __builtin_amdgcn_mfma_f32_16x16x32_bf16(af1, u2.b, acc1[2], 0, 0, 0);
        acc0[3] = __builtin_amdgcn_mfma_f32_16x16x32_bf16(af0, u3.b, acc0[3], 0, 0, 0);
        acc1[3] = __builtin_amdgcn_mfma_f32_16x16x32_bf16(af1, u3.b, acc1[3], 0, 0, 0);
    }

    // per-wave row-sums over this m-range
    ls0 += __shfl_xor(ls0, 16, 64); ls0 += __shfl_xor(ls0, 32, 64);
    ls1 += __shfl_xor(ls1, 16, 64); ls1 += __shfl_xor(ls1, 32, 64);

    // write partials (stride 35: conflict-free scalar access)
    float* myred = red + (w * 64 + lane) * 35;
#pragma unroll
    for (int ct = 0; ct < 4; ++ct)
#pragma unroll
        for (int r = 0; r < 4; ++r) {
            myred[ct * 4 + r]      = acc0[ct][r];
            myred[16 + ct * 4 + r] = acc1[ct][r];
        }
    myred[32] = ls0;
    myred[33] = ls1;
    __syncthreads();

    // combine: wave owns (subtile = w&1, ct pair = w>>1)
    const int tile = w & 1;
    const int ctp = w >> 1;
    float ltot = 0.f;
#pragma unroll
    for (int v4 = 0; v4 < 4; ++v4)
        ltot += red[(v4 * 64 + lane) * 35 + 32 + tile];
    float inv[4];
#pragma unroll
    for (int r = 0; r < 4; ++r)
        inv[r] = __builtin_amdgcn_rcpf(__shfl(ltot, quad * 4 + r, 16));

#pragma unroll
    for (int cti = 0; cti < 2; ++cti) {
        const int ct = ctp * 2 + cti;
        float facc[4] = {0.f, 0.f, 0.f, 0.f};
#pragma unroll
        for (int v4 = 0; v4 < 4; ++v4) {
            const float* rr = red + (v4 * 64 + lane) * 35 + tile * 16 + ct * 4;
#pragma unroll
            for (int r = 0; r < 4; ++r) facc[r] += rr[r];
        }
#pragma unroll
        for (int r = 0; r < 4; ++r) {
            int n = n0 + tile * 16 + quad * 4 + r;
            size_t off = (size_t)(b * 1024 + n) * 128 + hh * 64 + ct * 16 + col;
            float vv = facc[r] * inv[r] + hg[off];
            out[off] = vv > 0.f ? vv : __builtin_amdgcn_exp2f(vv * LOG2E) - 1.f;
        }
    }
}

// ---------------------------------------------------------------------------
extern "C" void kernel_launch(void* const* d_in, const int* in_sizes, int n_in,
                              void* d_out, int out_size, void* d_ws, size_t ws_size,
                              hipStream_t stream) {
    const float* h = (const float*)d_in[0];   // (16,1024,128)
    const float* W = (const float*)d_in[1];   // (2,128,64)
    const float* a = (const float*)d_in[2];   // (2,128,1)
    float* out = (float*)d_out;

    unsigned short* hpB = (unsigned short*)d_ws;                    // 4 MB
    float* es  = (float*)((char*)d_ws + (4u << 20));                // 128 KB
    float* ed  = es + 32 * 1024;                                    // 128 KB
    unsigned short* Wp = (unsigned short*)(ed + 32 * 1024);         // 32 KB
    float* acat = (float*)((char*)Wp + 16384 * sizeof(unsigned short));

    gat_prep<<<16, 256, 0, stream>>>(W, a, Wp, acat);
    gat_hp<<<512, 256, 0, stream>>>(h, Wp, acat, hpB, es, ed);
    gat_att<<<1024, 256, 0, stream>>>(h, hpB, es, ed, out);
}